// Round 6
// baseline (2677.379 us; speedup 1.0000x reference)
//
#include <hip/hip_runtime.h>
#include <math.h>

// ---------------------------------------------------------------------------
// GreyTransformer on MI355X — round 6: 4-wave wide-tile mgemm (128x96/192),
// round-4 attention (fences removed). Shapes: B=64, D_RNN=128, D=192, H=12,
// DH=16, NL=8, SEQ=400, NTOK=25600, T_NEW=2048.
// ---------------------------------------------------------------------------

typedef __attribute__((ext_vector_type(8))) __bf16 bf16x8;
typedef __attribute__((ext_vector_type(4))) float f32x4;

__device__ __forceinline__ float tanh_fast(float x) {
  float ax = fabsf(x);
  float e = __expf(-2.0f * ax);
  float r = (1.0f - e) / (1.0f + e);
  return x < 0.0f ? -r : r;
}

__device__ __forceinline__ float gelu_f(float x) {
  return 0.5f * x * (1.0f + erff(x * 0.70710678118654752f));
}

// Truncation split: v ~= hi + lo with |err| <~ 2^-16 relative.
__device__ __forceinline__ void split1(float v, unsigned short* hp, unsigned short* lp) {
  unsigned u = __float_as_uint(v);
  float hf = __uint_as_float(u & 0xffff0000u);
  *hp = (unsigned short)(u >> 16);
  *lp = (unsigned short)(__float_as_uint(v - hf) >> 16);
}

union B8 {
  unsigned short u[8];
  bf16x8 v;
};
union B4 {
  unsigned short u[4];
  ushort4 s4;
};

// ---------------------------------------------------------------------------
// Weight fp32 -> (hi, lo) bf16 planes.
// ---------------------------------------------------------------------------
__global__ __launch_bounds__(256) void cvt_kernel(
    const float* __restrict__ w, unsigned short* __restrict__ h,
    unsigned short* __restrict__ l, int n4)
{
  int i = blockIdx.x * 256 + threadIdx.x;
  if (i >= n4) return;
  float4 v = ((const float4*)w)[i];
  ushort4 hv, lv;
  split1(v.x, &hv.x, &lv.x);
  split1(v.y, &hv.y, &lv.y);
  split1(v.z, &hv.z, &lv.z);
  split1(v.w, &hv.w, &lv.w);
  ((ushort4*)h)[i] = hv;
  ((ushort4*)l)[i] = lv;
}

// ---------------------------------------------------------------------------
// MFMA RNN (unchanged; passing). 200 blocks x 128 seqs, 10 steps, hidden 128.
// ---------------------------------------------------------------------------
__global__ __launch_bounds__(256, 1) void rnn_kernel(
    const float* __restrict__ y, const float* __restrict__ u,
    const unsigned short* __restrict__ whh_h, const unsigned short* __restrict__ whh_l,
    const float* __restrict__ Wih, const float* __restrict__ bih,
    const float* __restrict__ bhh,
    unsigned short* __restrict__ hnh, unsigned short* __restrict__ hnl)
{
  __shared__ unsigned short Hh[128 * 136];
  __shared__ unsigned short Hl[128 * 136];
  __shared__ float yus[2][10][128];
  const int tid = threadIdx.x;
  const int sbase = blockIdx.x * 128;
  const int wid = tid >> 6, lane = tid & 63;
  const int quad = lane >> 4, r16 = lane & 15;
  const int mh = (wid & 1) * 64;
  const int sh = (wid >> 1) * 64;

  for (int idx = tid; idx < 1280; idx += 256) {
    int t = idx >> 7;
    int sl = idx & 127;
    int s = sbase + sl;
    int b = s / 400, p = s - b * 400;
    size_t g = (size_t)b * 4000 + p * 10 + t;
    yus[0][t][sl] = y[g];
    yus[1][t][sl] = u[g];
  }

  bf16x8 wf_h[4][4], wf_l[4][4];
#pragma unroll
  for (int mt = 0; mt < 4; ++mt)
#pragma unroll
    for (int kc = 0; kc < 4; ++kc) {
      size_t g = (size_t)(mh + mt * 16 + r16) * 128 + kc * 32 + quad * 8;
      wf_h[mt][kc] = *(const bf16x8*)(whh_h + g);
      wf_l[mt][kc] = *(const bf16x8*)(whh_l + g);
    }

  float b2r[4][4], war[4][4], wbr[4][4];
#pragma unroll
  for (int mt = 0; mt < 4; ++mt)
#pragma unroll
    for (int r = 0; r < 4; ++r) {
      int ho = mh + mt * 16 + quad * 4 + r;
      war[mt][r] = Wih[ho * 2 + 0];
      wbr[mt][r] = Wih[ho * 2 + 1];
      b2r[mt][r] = bih[ho] + bhh[ho];
    }
  __syncthreads();

  f32x4 acc[4][4];
  for (int t = 0; t < 10; ++t) {
    float yv[4], uv[4];
#pragma unroll
    for (int nt = 0; nt < 4; ++nt) {
      int s = sh + nt * 16 + r16;
      yv[nt] = yus[0][t][s];
      uv[nt] = yus[1][t][s];
    }
#pragma unroll
    for (int mt = 0; mt < 4; ++mt)
#pragma unroll
      for (int nt = 0; nt < 4; ++nt)
#pragma unroll
        for (int r = 0; r < 4; ++r)
          acc[mt][nt][r] = b2r[mt][r] + war[mt][r] * yv[nt] + wbr[mt][r] * uv[nt];

    if (t > 0) {
#pragma unroll
      for (int kc = 0; kc < 4; ++kc) {
        bf16x8 bhf[4], blf[4];
#pragma unroll
        for (int nt = 0; nt < 4; ++nt) {
          int a = (sh + nt * 16 + r16) * 136 + kc * 32 + quad * 8;
          bhf[nt] = *(const bf16x8*)&Hh[a];
          blf[nt] = *(const bf16x8*)&Hl[a];
        }
#pragma unroll
        for (int mt = 0; mt < 4; ++mt)
#pragma unroll
          for (int nt = 0; nt < 4; ++nt) {
            acc[mt][nt] = __builtin_amdgcn_mfma_f32_16x16x32_bf16(wf_h[mt][kc], bhf[nt], acc[mt][nt], 0, 0, 0);
            acc[mt][nt] = __builtin_amdgcn_mfma_f32_16x16x32_bf16(wf_l[mt][kc], bhf[nt], acc[mt][nt], 0, 0, 0);
            acc[mt][nt] = __builtin_amdgcn_mfma_f32_16x16x32_bf16(wf_h[mt][kc], blf[nt], acc[mt][nt], 0, 0, 0);
          }
      }
      __syncthreads();
    }

#pragma unroll
    for (int mt = 0; mt < 4; ++mt)
#pragma unroll
      for (int nt = 0; nt < 4; ++nt) {
        B4 hi4, lo4;
#pragma unroll
        for (int r = 0; r < 4; ++r) {
          float hv = tanh_fast(acc[mt][nt][r]);
          split1(hv, &hi4.u[r], &lo4.u[r]);
        }
        int s = sh + nt * 16 + r16;
        int off = s * 136 + mh + mt * 16 + quad * 4;
        *(ushort4*)&Hh[off] = hi4.s4;
        *(ushort4*)&Hl[off] = lo4.s4;
      }
    __syncthreads();
  }

  for (int idx = tid; idx < 2048; idx += 256) {
    int row = idx >> 4, c = (idx & 15) * 8;
    size_t g = (size_t)(sbase + row) * 128 + c;
    *(bf16x8*)(hnh + g) = *(const bf16x8*)&Hh[row * 136 + c];
    *(bf16x8*)(hnl + g) = *(const bf16x8*)&Hl[row * 136 + c];
  }
}

// ---------------------------------------------------------------------------
// Split-bf16 MFMA GEMM, 4 waves (2m x 2n), tile 128 x (32*NT), BK=32.
// Per wave: 64 x (16*NT). D = Ah*Wh + Al*Wh + Ah*Wl.
// NT=6 -> BN=192 (qkv/fc), NT=3 -> BN=96 (wo/proj/enc).
// EPI: 0 none->f32, 1 +res->f32, 2 gelu->bf16 planes, 3 bias+posenc->f32.
// ---------------------------------------------------------------------------
template <int NT, int EPI>
__global__ __launch_bounds__(256) void mgemm(
    const unsigned short* __restrict__ Agh, const unsigned short* __restrict__ Agl,
    int lda,
    const unsigned short* __restrict__ Wgh, const unsigned short* __restrict__ Wgl,
    const float* __restrict__ bias, const float* __restrict__ res,
    float* __restrict__ C, unsigned short* __restrict__ Ch,
    unsigned short* __restrict__ Cl, int M, int N, int K)
{
  constexpr int BN = 32 * NT;
  __shared__ unsigned short AhL[128 * 40];
  __shared__ unsigned short AlL[128 * 40];
  __shared__ unsigned short WhL[BN * 40];
  __shared__ unsigned short WlL[BN * 40];
  const int tid = threadIdx.x;
  const int wid = tid >> 6, lane = tid & 63;
  const int quad = lane >> 4, r16 = lane & 15;
  const int m0 = blockIdx.x * 128, n0 = blockIdx.y * BN;
  const int mbase = (wid & 1) * 64;
  const int nbase = (wid >> 1) * 16 * NT;
  f32x4 acc[4][NT] = {};

  for (int k0 = 0; k0 < K; k0 += 32) {
    // stage A (128 rows x 32k, hi+lo): 512 chunk-units over 256 threads
#pragma unroll
    for (int r = 0; r < 2; ++r) {
      int idx = tid + r * 256;
      int row = idx >> 2, c = (idx & 3) * 8;
      size_t g = (size_t)(m0 + row) * lda + k0 + c;
      *(bf16x8*)&AhL[row * 40 + c] = *(const bf16x8*)(Agh + g);
      *(bf16x8*)&AlL[row * 40 + c] = *(const bf16x8*)(Agl + g);
    }
    // stage W (BN rows x 32k, hi+lo): BN*4 chunk-units
    for (int idx = tid; idx < BN * 4; idx += 256) {
      int row = idx >> 2, c = (idx & 3) * 8;
      size_t g = (size_t)(n0 + row) * K + k0 + c;
      *(bf16x8*)&WhL[row * 40 + c] = *(const bf16x8*)(Wgh + g);
      *(bf16x8*)&WlL[row * 40 + c] = *(const bf16x8*)(Wgl + g);
    }
    __syncthreads();
    bf16x8 ah[4], al[4];
#pragma unroll
    for (int t = 0; t < 4; ++t) {
      int ra = (mbase + t * 16 + r16) * 40 + quad * 8;
      ah[t] = *(const bf16x8*)&AhL[ra];
      al[t] = *(const bf16x8*)&AlL[ra];
    }
#pragma unroll
    for (int nt = 0; nt < NT; ++nt) {
      int rb = (nbase + nt * 16 + r16) * 40 + quad * 8;
      bf16x8 bh = *(const bf16x8*)&WhL[rb];
      bf16x8 bl = *(const bf16x8*)&WlL[rb];
#pragma unroll
      for (int mt = 0; mt < 4; ++mt) {
        acc[mt][nt] = __builtin_amdgcn_mfma_f32_16x16x32_bf16(ah[mt], bh, acc[mt][nt], 0, 0, 0);
        acc[mt][nt] = __builtin_amdgcn_mfma_f32_16x16x32_bf16(al[mt], bh, acc[mt][nt], 0, 0, 0);
        acc[mt][nt] = __builtin_amdgcn_mfma_f32_16x16x32_bf16(ah[mt], bl, acc[mt][nt], 0, 0, 0);
      }
    }
    __syncthreads();
  }

  // Epilogue. C/D layout: col = r16 (n), row = quad*4 + r (m).
#pragma unroll
  for (int mt = 0; mt < 4; ++mt)
#pragma unroll
    for (int nt = 0; nt < NT; ++nt)
#pragma unroll
      for (int r = 0; r < 4; ++r) {
        int m = m0 + mbase + mt * 16 + quad * 4 + r;
        int n = n0 + nbase + nt * 16 + r16;
        float v = acc[mt][nt][r];
        if (EPI == 3) {
          v += bias[n];
          int p = m % 400;
          float freq = __expf((float)(n & ~1) * (-9.210340371976184f / 192.f));
          float ang = (float)p * freq;
          v += (n & 1) ? cosf(ang) : sinf(ang);
        }
        if (EPI == 1) v += res[(size_t)m * N + n];
        if (EPI == 2) {
          v = gelu_f(v);
          size_t g = (size_t)m * N + n;
          split1(v, &Ch[g], &Cl[g]);
        } else {
          C[(size_t)m * N + n] = v;
        }
      }
}

// ---------------------------------------------------------------------------
// LayerNorm over 192.
// ---------------------------------------------------------------------------
template <bool BF16OUT>
__global__ __launch_bounds__(256) void ln_kernel(
    const float* __restrict__ x, const float* __restrict__ w,
    float* __restrict__ outf, unsigned short* __restrict__ oh,
    unsigned short* __restrict__ ol)
{
  int token = blockIdx.x * 4 + (threadIdx.x >> 6);
  int lane = threadIdx.x & 63;
  const float* xp = x + (size_t)token * 192;
  float v0 = xp[lane], v1 = xp[lane + 64], v2 = xp[lane + 128];
  float s = v0 + v1 + v2;
  float sq = v0 * v0 + v1 * v1 + v2 * v2;
#pragma unroll
  for (int off = 32; off >= 1; off >>= 1) {
    s += __shfl_xor(s, off, 64);
    sq += __shfl_xor(sq, off, 64);
  }
  float mean = s * (1.f / 192.f);
  float var = sq * (1.f / 192.f) - mean * mean;
  float rstd = rsqrtf(var + 1e-5f);
  float o0 = (v0 - mean) * rstd * w[lane];
  float o1 = (v1 - mean) * rstd * w[lane + 64];
  float o2 = (v2 - mean) * rstd * w[lane + 128];
  size_t base = (size_t)token * 192;
  if (BF16OUT) {
    split1(o0, &oh[base + lane], &ol[base + lane]);
    split1(o1, &oh[base + lane + 64], &ol[base + lane + 64]);
    split1(o2, &oh[base + lane + 128], &ol[base + lane + 128]);
  } else {
    outf[base + lane] = o0;
    outf[base + lane + 64] = o1;
    outf[base + lane + 128] = o2;
  }
}

// ---------------------------------------------------------------------------
// MFMA attention (round-4 structure, fences removed, shfl for linv).
// One block per (b,h), 256 threads = 4 waves. LDS ~68.6 KB.
// ---------------------------------------------------------------------------
__global__ __launch_bounds__(256) void attn_kernel(
    const float* __restrict__ qkv, unsigned short* __restrict__ oh,
    unsigned short* __restrict__ ol)
{
  __shared__ unsigned short KC[400 * 40];
  __shared__ unsigned short VTh[16 * 424];
  __shared__ unsigned short VTl[16 * 424];
  __shared__ unsigned short Pst[4][16 * 36 * 2];
  const int tid = threadIdx.x;
  const int bh = blockIdx.x;
  const int b = bh / 12;
  const int h = bh - b * 12;
  const float* base = qkv + (size_t)b * 400 * 576;

  for (int idx = tid; idx < 16 * 24; idx += 256) {
    int d = idx / 24;
    int j = 400 + idx % 24;
    VTh[d * 424 + j] = 0;
    VTl[d * 424 + j] = 0;
  }
  for (int it = tid; it < 1600; it += 256) {
    int j = it >> 2, d4 = (it & 3) << 2;
    const float* rp = base + (size_t)j * 576 + h * 16 + d4;
    float4 kv = *(const float4*)(rp + 192);
    float4 vv = *(const float4*)(rp + 384);
    B4 kh, kl;
    split1(kv.x, &kh.u[0], &kl.u[0]);
    split1(kv.y, &kh.u[1], &kl.u[1]);
    split1(kv.z, &kh.u[2], &kl.u[2]);
    split1(kv.w, &kh.u[3], &kl.u[3]);
    *(ushort4*)&KC[j * 40 + d4] = kh.s4;
    *(ushort4*)&KC[j * 40 + 16 + d4] = kl.s4;
    unsigned short vh[4], vl[4];
    split1(vv.x, &vh[0], &vl[0]);
    split1(vv.y, &vh[1], &vl[1]);
    split1(vv.z, &vh[2], &vl[2]);
    split1(vv.w, &vh[3], &vl[3]);
#pragma unroll
    for (int k = 0; k < 4; ++k) {
      VTh[(d4 + k) * 424 + j] = vh[k];
      VTl[(d4 + k) * 424 + j] = vl[k];
    }
  }
  __syncthreads();

  const int wid = tid >> 6, lane = tid & 63;
  const int quad = lane >> 4, r16 = lane & 15;
  unsigned short* Ph = &Pst[wid][0];
  unsigned short* Pl = &Pst[wid][576];

  for (int qt = wid; qt < 25; qt += 4) {
    // ---- Q fragments: [Qh|Ql] and [Ql|Qh] along k
    const float* qp = base + (size_t)(qt * 16 + r16) * 576 + h * 16 + ((quad & 1) * 8);
    float4 q0 = *(const float4*)qp;
    float4 q1 = *(const float4*)(qp + 4);
    float qv[8] = {q0.x, q0.y, q0.z, q0.w, q1.x, q1.y, q1.z, q1.w};
    B8 qh, ql;
#pragma unroll
    for (int i = 0; i < 8; ++i) split1(qv[i], &qh.u[i], &ql.u[i]);
    bf16x8 B1 = (quad < 2) ? qh.v : ql.v;
    bf16x8 B2 = (quad < 2) ? ql.v : qh.v;

    // ---- S^T tiles
    f32x4 acc[25];
#pragma unroll
    for (int jt = 0; jt < 25; ++jt) {
      bf16x8 A = *(const bf16x8*)&KC[(jt * 16 + r16) * 40 + quad * 8];
      f32x4 a = {0.f, 0.f, 0.f, 0.f};
      a = __builtin_amdgcn_mfma_f32_16x16x32_bf16(A, B1, a, 0, 0, 0);
      a = __builtin_amdgcn_mfma_f32_16x16x32_bf16(A, B2, a, 0, 0, 0);
      acc[jt] = a;
    }

    // ---- softmax (scale 0.25 folded into exp arg)
    float mx = -INFINITY;
#pragma unroll
    for (int jt = 0; jt < 25; ++jt)
#pragma unroll
      for (int r = 0; r < 4; ++r) mx = fmaxf(mx, acc[jt][r]);
    mx = fmaxf(mx, __shfl_xor(mx, 16, 64));
    mx = fmaxf(mx, __shfl_xor(mx, 32, 64));
    float mm = 0.25f * mx;
    float lsum = 0.f;
#pragma unroll
    for (int jt = 0; jt < 25; ++jt)
#pragma unroll
      for (int r = 0; r < 4; ++r) {
        float p = __expf(fmaf(0.25f, acc[jt][r], -mm));
        acc[jt][r] = p;
        lsum += p;
      }
    lsum += __shfl_xor(lsum, 16, 64);
    lsum += __shfl_xor(lsum, 32, 64);
    float linv = 1.f / lsum;   // lane holds value for column q = r16

    // ---- PV over 13 chunks of 32 j (single-buffer bounce, no fences)
    f32x4 O = {0.f, 0.f, 0.f, 0.f};
#pragma unroll
    for (int c = 0; c < 13; ++c) {
      {
        B4 ph, pl;
        f32x4 p = acc[2 * c];
        split1(p[0], &ph.u[0], &pl.u[0]);
        split1(p[1], &ph.u[1], &pl.u[1]);
        split1(p[2], &ph.u[2], &pl.u[2]);
        split1(p[3], &ph.u[3], &pl.u[3]);
        *(ushort4*)&Ph[r16 * 36 + quad * 4] = ph.s4;
        *(ushort4*)&Pl[r16 * 36 + quad * 4] = pl.s4;
      }
      if (c < 12) {
        B4 ph, pl;
        f32x4 p = acc[2 * c + 1];
        split1(p[0], &ph.u[0], &pl.u[0]);
        split1(p[1], &ph.u[1], &pl.u[1]);
        split1(p[2], &ph.u[2], &pl.u[2]);
        split1(p[3], &ph.u[3], &pl.u[3]);
        *(ushort4*)&Ph[r16 * 36 + 16 + quad * 4] = ph.s4;
        *(ushort4*)&Pl[r16 * 36 + 16 + quad * 4] = pl.s4;
      } else {
        ushort4 z = {0, 0, 0, 0};
        *(ushort4*)&Ph[r16 * 36 + 16 + quad * 4] = z;
        *(ushort4*)&Pl[r16 * 36 + 16 + quad * 4] = z;
      }
      bf16x8 Ah = *(const bf16x8*)&Ph[r16 * 36 + quad * 8];
      bf16x8 Al = *(const bf16x8*)&Pl[r16 * 36 + quad * 8];
      bf16x8 Vh = *(const bf16x8*)&VTh[r16 * 424 + c * 32 + quad * 8];
      bf16x8 Vl = *(const bf16x8*)&VTl[r16 * 424 + c * 32 + quad * 8];
      O = __builtin_amdgcn_mfma_f32_16x16x32_bf16(Ah, Vh, O, 0, 0, 0);
      O = __builtin_amdgcn_mfma_f32_16x16x32_bf16(Al, Vh, O, 0, 0, 0);
      O = __builtin_amdgcn_mfma_f32_16x16x32_bf16(Ah, Vl, O, 0, 0, 0);
    }

    // ---- epilogue: O C-layout col=d=r16, row=q_local=quad*4+r
#pragma unroll
    for (int r = 0; r < 4; ++r) {
      float lv = __shfl(linv, quad * 4 + r, 16);
      float v = O[r] * lv;
      size_t g = (size_t)(b * 400 + qt * 16 + quad * 4 + r) * 192 + h * 16 + r16;
      split1(v, &oh[g], &ol[g]);
    }
  }
}

// ---------------------------------------------------------------------------
// Mean-pool over seq (400).
// ---------------------------------------------------------------------------
__global__ void pool_kernel(const float* __restrict__ xln, float* __restrict__ pooled)
{
  int b = blockIdx.x;
  int d = threadIdx.x;  // 192
  const float* p = xln + (size_t)b * 400 * 192 + d;
  float s = 0.f;
  for (int t = 0; t < 400; ++t) s += p[(size_t)t * 192];
  pooled[b * 192 + d] = s * (1.f / 400.f);
}

// ---------------------------------------------------------------------------
// Small fp32 GEMM for pooled @ proj_W^T + b (M=64).
// ---------------------------------------------------------------------------
__global__ __launch_bounds__(256) void sgemm_kernel(
    const float* __restrict__ A, const float* __restrict__ W,
    const float* __restrict__ bias, float* __restrict__ C,
    int M, int N, int K)
{
  __shared__ float As[16][128];
  __shared__ float Ws[16][64];
  const int tid = threadIdx.x;
  const int m0 = blockIdx.x * 128;
  const int n0 = blockIdx.y * 64;
  const int tx = tid & 15;
  const int ty = tid >> 4;
  float acc[8][4] = {};

  for (int k0 = 0; k0 < K; k0 += 16) {
    int id = tid;
#pragma unroll
    for (int r = 0; r < 2; ++r, id += 256) {
      int kg = (id & 3) << 2;
      int m = id >> 2;
      float4 v = make_float4(0.f, 0.f, 0.f, 0.f);
      if ((m0 + m) < M)
        v = *(const float4*)(A + (size_t)(m0 + m) * K + k0 + kg);
      As[kg + 0][m] = v.x; As[kg + 1][m] = v.y;
      As[kg + 2][m] = v.z; As[kg + 3][m] = v.w;
    }
    {
      int kg = (tid & 3) << 2;
      int n = tid >> 2;
      float4 v = *(const float4*)(W + (size_t)(n0 + n) * K + k0 + kg);
      Ws[kg + 0][n] = v.x; Ws[kg + 1][n] = v.y;
      Ws[kg + 2][n] = v.z; Ws[kg + 3][n] = v.w;
    }
    __syncthreads();
#pragma unroll
    for (int kk = 0; kk < 16; ++kk) {
      float4 a0 = *(const float4*)&As[kk][ty * 8];
      float4 a1 = *(const float4*)&As[kk][ty * 8 + 4];
      float4 b4 = *(const float4*)&Ws[kk][tx * 4];
      float av[8] = {a0.x, a0.y, a0.z, a0.w, a1.x, a1.y, a1.z, a1.w};
      float bv[4] = {b4.x, b4.y, b4.z, b4.w};
#pragma unroll
      for (int i = 0; i < 8; ++i)
#pragma unroll
        for (int j = 0; j < 4; ++j)
          acc[i][j] += av[i] * bv[j];
    }
    __syncthreads();
  }
  float4 bvz = *(const float4*)(bias + n0 + tx * 4);
#pragma unroll
  for (int i = 0; i < 8; ++i) {
    int m = m0 + ty * 8 + i;
    if (m >= M) continue;
    int n = n0 + tx * 4;
    float4 outv = make_float4(acc[i][0] + bvz.x, acc[i][1] + bvz.y,
                              acc[i][2] + bvz.z, acc[i][3] + bvz.w);
    *(float4*)(C + (size_t)m * N + n) = outv;
  }
}

// ---------------------------------------------------------------------------
// Final LDS scans (chunk-parallel affine recurrence). One block per batch.
// ---------------------------------------------------------------------------
__global__ __launch_bounds__(64) void lds_kernel(
    const float* __restrict__ params, const float* __restrict__ u_new,
    float* __restrict__ out)
{
  __shared__ float P[192];
  __shared__ float ubuf[2048];
  __shared__ float fbuf[2048];
  __shared__ float dv[64][5];
  __shared__ float xin[64][5];
  const int b = blockIdx.x;
  const int c = threadIdx.x;
  for (int k = c; k < 192; k += 64) P[k] = params[b * 192 + k];
  for (int i = c; i < 2048; i += 64) ubuf[i] = u_new[(size_t)b * 2048 + i];
  __syncthreads();

  float A1[25], B1v[5], C1v[5], D1s, w1[29], b1v[29], w2[29], b2s;
  float A2[25], B2v[5], C2v[5], D2s;
#pragma unroll
  for (int i = 0; i < 25; ++i) A1[i] = P[i];
#pragma unroll
  for (int i = 0; i < 5; ++i) B1v[i] = P[25 + i];
#pragma unroll
  for (int i = 0; i < 5; ++i) C1v[i] = P[30 + i];
  D1s = P[35];
#pragma unroll
  for (int i = 0; i < 29; ++i) w1[i] = P[36 + i];
#pragma unroll
  for (int i = 0; i < 29; ++i) b1v[i] = P[65 + i];
#pragma unroll
  for (int i = 0; i < 29; ++i) w2[i] = P[94 + i];
  b2s = P[123];
#pragma unroll
  for (int i = 0; i < 25; ++i) A2[i] = P[124 + i];
#pragma unroll
  for (int i = 0; i < 5; ++i) B2v[i] = P[149 + i];
#pragma unroll
  for (int i = 0; i < 5; ++i) C2v[i] = P[154 + i];
  D2s = P[159];

  const int t0 = c * 32;
  float s1[5] = {0, 0, 0, 0, 0};
  for (int t = 0; t < 32; ++t) {
    float ut = ubuf[t0 + t];
    float ns[5];
#pragma unroll
    for (int i = 0; i < 5; ++i) {
      float a = B1v[i] * ut;
#pragma unroll
      for (int j = 0; j < 5; ++j) a += A1[i * 5 + j] * s1[j];
      ns[i] = a;
    }
#pragma unroll
    for (int i = 0; i < 5; ++i) s1[i] = ns[i];
  }
#pragma unroll
  for (int i = 0; i < 5; ++i) dv[c][i] = s1[i];
  __syncthreads();
  if (c == 0) {
    float Pm[25], T[25];
#pragma unroll
    for (int i = 0; i < 25; ++i) Pm[i] = A1[i];
    for (int it = 0; it < 5; ++it) {
#pragma unroll
      for (int i = 0; i < 5; ++i)
#pragma unroll
        for (int j = 0; j < 5; ++j) {
          float a = 0.f;
#pragma unroll
          for (int k = 0; k < 5; ++k) a += Pm[i * 5 + k] * Pm[k * 5 + j];
          T[i * 5 + j] = a;
        }
#pragma unroll
      for (int i = 0; i < 25; ++i) Pm[i] = T[i];
    }
    float xs[5] = {0, 0, 0, 0, 0};
    for (int cc = 0; cc < 64; ++cc) {
#pragma unroll
      for (int i = 0; i < 5; ++i) xin[cc][i] = xs[i];
      float nx[5];
#pragma unroll
      for (int i = 0; i < 5; ++i) {
        float a = dv[cc][i];
#pragma unroll
        for (int j = 0; j < 5; ++j) a += Pm[i * 5 + j] * xs[j];
        nx[i] = a;
      }
#pragma unroll
      for (int i = 0; i < 5; ++i) xs[i] = nx[i];
    }
  }
  __syncthreads();
#pragma unroll
  for (int i = 0; i < 5; ++i) s1[i] = xin[c][i];
  float s2[5] = {0, 0, 0, 0, 0};
  for (int t = 0; t < 32; ++t) {
    float ut = ubuf[t0 + t];
    float ns[5];
#pragma unroll
    for (int i = 0; i < 5; ++i) {
      float a = B1v[i] * ut;
#pragma unroll
      for (int j = 0; j < 5; ++j) a += A1[i * 5 + j] * s1[j];
      ns[i] = a;
    }
#pragma unroll
    for (int i = 0; i < 5; ++i) s1[i] = ns[i];
    float y1 = D1s * ut;
#pragma unroll
    for (int j = 0; j < 5; ++j) y1 += C1v[j] * s1[j];
    float f = b2s;
#pragma unroll
    for (int k = 0; k < 29; ++k) f += tanh_fast(y1 * w1[k] + b1v[k]) * w2[k];
    fbuf[t0 + t] = f;
#pragma unroll
    for (int i = 0; i < 5; ++i) {
      float a = B2v[i] * f;
#pragma unroll
      for (int j = 0; j < 5; ++j) a += A2[i * 5 + j] * s2[j];
      ns[i] = a;
    }
#pragma unroll
    for (int i = 0; i < 5; ++i) s2[i] = ns[i];
  }
#pragma unroll
  for (int i = 0; i < 5; ++i) dv[c][i] = s2[i];
  __syncthreads();
  if (c == 0) {
    float Pm[25], T[25];
#pragma unroll
    for (int i = 0; i < 25; ++i) Pm[i] = A2[i];
    for (int it = 0; it < 5; ++it) {
#pragma unroll
      for (int i = 0; i < 5; ++i)
#pragma unroll
        for (int j = 0; j < 5; ++j) {
          float a = 0.f;
#pragma unroll
          for (int k = 0; k < 5; ++k) a += Pm[i * 5 + k] * Pm[k * 5 + j];
          T[i * 5 + j] = a;
        }
#pragma unroll
      for (int i = 0; i < 25; ++i) Pm[i] = T[i];
    }
    float xs[5] = {0, 0, 0, 0, 0};
    for (int cc = 0; cc < 64; ++cc) {
#pragma unroll
      for (int i = 0; i < 5; ++i) xin[cc][i] = xs[i];
      float nx[5];
#pragma unroll
      for (int i = 0; i < 5; ++i) {
        float a = dv[cc][i];
#pragma unroll
        for (int j = 0; j < 5; ++j) a += Pm[i * 5 + j] * xs[j];
        nx[i] = a;
      }
#pragma unroll
      for (int i = 0; i < 5; ++i) xs[i] = nx[i];
    }
  }
  __syncthreads();
#pragma unroll
  for (int i = 0; i < 5; ++i) s2[i] = xin[c][i];
  float lsum = 0.f;
  for (int t = 0; t < 32; ++t) {
    float ft = fbuf[t0 + t];
    float ns[5];
#pragma unroll
    for (int i = 0; i < 5; ++i) {
      float a = B2v[i] * ft;
#pragma unroll
      for (int j = 0; j < 5; ++j) a += A2[i * 5 + j] * s2[j];
      ns[i] = a;
    }
#pragma unroll
    for (int i = 0; i < 5; ++i) s2[i] = ns[i];
    float ov = D2s * ft;
#pragma unroll
    for (int j = 0; j < 5; ++j) ov += C2v[j] * s2[j];
    ubuf[t0 + t] = ov;
    lsum += ov;
  }
#pragma unroll
  for (int off = 32; off >= 1; off >>= 1) lsum += __shfl_xor(lsum, off, 64);
  float mean = lsum * (1.f / 2048.f);
  __syncthreads();
  for (int i = c; i < 2048; i += 64)
    out[(size_t)b * 2048 + i] = ubuf[i] - mean;
}

// ---------------------------------------------------------------------------
extern "C" void kernel_launch(void* const* d_in, const int* in_sizes, int n_in,
                              void* d_out, int out_size, void* d_ws, size_t ws_size,
                              hipStream_t stream)
{
  (void)in_sizes; (void)n_in; (void)out_size; (void)ws_size;
  const float* y       = (const float*)d_in[0];
  const float* u       = (const float*)d_in[1];
  const float* u_new   = (const float*)d_in[2];
  const float* rnn_Wih = (const float*)d_in[3];
  const float* rnn_Whh = (const float*)d_in[4];
  const float* rnn_bih = (const float*)d_in[5];
  const float* rnn_bhh = (const float*)d_in[6];
  const float* wte_W   = (const float*)d_in[7];
  const float* wte_b   = (const float*)d_in[8];
  const float* ln1_w   = (const float*)d_in[9];
  const float* Wqkv    = (const float*)d_in[10];
  const float* Wo      = (const float*)d_in[11];
  const float* ln2_w   = (const float*)d_in[12];
  const float* Wfc     = (const float*)d_in[13];
  const float* Wproj   = (const float*)d_in[14];
  const float* lnf_w   = (const float*)d_in[15];
  const float* proj_W  = (const float*)d_in[16];
  const float* proj_b  = (const float*)d_in[17];
  float* out = (float*)d_out;
  char* wsb = (char*)d_ws;

  // ---- workspace layout ----
  float* x      = (float*)wsb;                               // 4,915,200 f
  float* bigf   = x + 4915200;                               // 14,745,600 f
  float* pooled = bigf + 14745600;                           // 12,288 f
  float* paramsv = pooled + 12288;                           // 12,288 f
  unsigned short* aA_h = (unsigned short*)(paramsv + 12288); // 25600*192
  unsigned short* aA_l = aA_h + 4915200;
  unsigned short* aB_h = aA_l + 4915200;                     // 25600*768
  unsigned short* aB_l = aB_h + 19660800;
  unsigned short* w_h  = aB_l + 19660800;                    // 3,563,520
  unsigned short* w_l  = w_h + 3563520;
  unsigned short* whh_h = w_l + 3563520;                     // 16,384
  unsigned short* whh_l = whh_h + 16384;
  const size_t OFF_ENC = 0;
  const size_t OFF_QKV = 24576;
  const size_t OFF_WO  = 909312;
  const size_t OFF_FC  = 1204224;
  const size_t OFF_PRJ = 2383872;

  cvt_kernel<<<(6144 + 255) / 256, 256, 0, stream>>>(wte_W, w_h + OFF_ENC, w_l + OFF_ENC, 6144);
  cvt_kernel<<<(221184 + 255) / 256, 256, 0, stream>>>(Wqkv, w_h + OFF_QKV, w_l + OFF_QKV, 221184);
  cvt_kernel<<<(73728 + 255) / 256, 256, 0, stream>>>(Wo, w_h + OFF_WO, w_l + OFF_WO, 73728);
  cvt_kernel<<<(294912 + 255) / 256, 256, 0, stream>>>(Wfc, w_h + OFF_FC, w_l + OFF_FC, 294912);
  cvt_kernel<<<(294912 + 255) / 256, 256, 0, stream>>>(Wproj, w_h + OFF_PRJ, w_l + OFF_PRJ, 294912);
  cvt_kernel<<<16, 256, 0, stream>>>(rnn_Whh, whh_h, whh_l, 4096);

  rnn_kernel<<<200, 256, 0, stream>>>(y, u, whh_h, whh_l, rnn_Wih, rnn_bih, rnn_bhh, aA_h, aA_l);

  // encoder: x = hn @ wte_W^T + b + posenc  (N=192 -> NT=3, y=2)
  mgemm<3, 3><<<dim3(200, 2), 256, 0, stream>>>(
      aA_h, aA_l, 128, w_h + OFF_ENC, w_l + OFF_ENC, wte_b, nullptr,
      x, nullptr, nullptr, 25600, 192, 128);

  for (int l = 0; l < 8; ++l) {
    ln_kernel<true><<<6400, 256, 0, stream>>>(x, ln1_w + l * 192, nullptr, aA_h, aA_l);
    mgemm<6, 0><<<dim3(200, 3), 256, 0, stream>>>(
        aA_h, aA_l, 192, w_h + OFF_QKV + (size_t)l * 110592, w_l + OFF_QKV + (size_t)l * 110592,
        nullptr, nullptr, bigf, nullptr, nullptr, 25600, 576, 192);
    attn_kernel<<<768, 256, 0, stream>>>(bigf, aA_h, aA_l);
    mgemm<3, 1><<<dim3(200, 2), 256, 0, stream>>>(
        aA_h, aA_l, 192, w_h + OFF_WO + (size_t)l * 36864, w_l + OFF_WO + (size_t)l * 36864,
        nullptr, x, x, nullptr, nullptr, 25600, 192, 192);
    ln_kernel<true><<<6400, 256, 0, stream>>>(x, ln2_w + l * 192, nullptr, aA_h, aA_l);
    mgemm<6, 2><<<dim3(200, 4), 256, 0, stream>>>(
        aA_h, aA_l, 192, w_h + OFF_FC + (size_t)l * 147456, w_l + OFF_FC + (size_t)l * 147456,
        nullptr, nullptr, nullptr, aB_h, aB_l, 25600, 768, 192);
    mgemm<3, 1><<<dim3(200, 2), 256, 0, stream>>>(
        aB_h, aB_l, 768, w_h + OFF_PRJ + (size_t)l * 147456, w_l + OFF_PRJ + (size_t)l * 147456,
        nullptr, x, x, nullptr, nullptr, 25600, 192, 768);
  }

  ln_kernel<false><<<6400, 256, 0, stream>>>(x, lnf_w, bigf, nullptr, nullptr);
  pool_kernel<<<64, 192, 0, stream>>>(bigf, pooled);
  sgemm_kernel<<<dim3(1, 3), 256, 0, stream>>>(pooled, proj_W, proj_b, paramsv, 64, 192, 192);
  lds_kernel<<<64, 64, 0, stream>>>(paramsv, u_new, out);
}

// Round 7
// 2316.005 us; speedup vs baseline: 1.1560x; 1.1560x over previous
//
#include <hip/hip_runtime.h>
#include <math.h>

// ---------------------------------------------------------------------------
// GreyTransformer on MI355X — round 7: 8-wave round-4 attention (fences kept,
// 2x occupancy), round-5 register-prefetch mgemm. Shapes: B=64, D_RNN=128,
// D=192, H=12, DH=16, NL=8, SEQ=400, NTOK=25600, T_NEW=2048.
// ---------------------------------------------------------------------------

typedef __attribute__((ext_vector_type(8))) __bf16 bf16x8;
typedef __attribute__((ext_vector_type(4))) float f32x4;

__device__ __forceinline__ float tanh_fast(float x) {
  float ax = fabsf(x);
  float e = __expf(-2.0f * ax);
  float r = (1.0f - e) / (1.0f + e);
  return x < 0.0f ? -r : r;
}

__device__ __forceinline__ float gelu_f(float x) {
  return 0.5f * x * (1.0f + erff(x * 0.70710678118654752f));
}

// Truncation split: v ~= hi + lo with |err| <~ 2^-16 relative.
__device__ __forceinline__ void split1(float v, unsigned short* hp, unsigned short* lp) {
  unsigned u = __float_as_uint(v);
  float hf = __uint_as_float(u & 0xffff0000u);
  *hp = (unsigned short)(u >> 16);
  *lp = (unsigned short)(__float_as_uint(v - hf) >> 16);
}

union B8 {
  unsigned short u[8];
  bf16x8 v;
};
union B4 {
  unsigned short u[4];
  ushort4 s4;
};

// ---------------------------------------------------------------------------
// Weight fp32 -> (hi, lo) bf16 planes.
// ---------------------------------------------------------------------------
__global__ __launch_bounds__(256) void cvt_kernel(
    const float* __restrict__ w, unsigned short* __restrict__ h,
    unsigned short* __restrict__ l, int n4)
{
  int i = blockIdx.x * 256 + threadIdx.x;
  if (i >= n4) return;
  float4 v = ((const float4*)w)[i];
  ushort4 hv, lv;
  split1(v.x, &hv.x, &lv.x);
  split1(v.y, &hv.y, &lv.y);
  split1(v.z, &hv.z, &lv.z);
  split1(v.w, &hv.w, &lv.w);
  ((ushort4*)h)[i] = hv;
  ((ushort4*)l)[i] = lv;
}

// ---------------------------------------------------------------------------
// MFMA RNN (unchanged; passing). 200 blocks x 128 seqs, 10 steps, hidden 128.
// ---------------------------------------------------------------------------
__global__ __launch_bounds__(256, 1) void rnn_kernel(
    const float* __restrict__ y, const float* __restrict__ u,
    const unsigned short* __restrict__ whh_h, const unsigned short* __restrict__ whh_l,
    const float* __restrict__ Wih, const float* __restrict__ bih,
    const float* __restrict__ bhh,
    unsigned short* __restrict__ hnh, unsigned short* __restrict__ hnl)
{
  __shared__ unsigned short Hh[128 * 136];
  __shared__ unsigned short Hl[128 * 136];
  __shared__ float yus[2][10][128];
  const int tid = threadIdx.x;
  const int sbase = blockIdx.x * 128;
  const int wid = tid >> 6, lane = tid & 63;
  const int quad = lane >> 4, r16 = lane & 15;
  const int mh = (wid & 1) * 64;
  const int sh = (wid >> 1) * 64;

  for (int idx = tid; idx < 1280; idx += 256) {
    int t = idx >> 7;
    int sl = idx & 127;
    int s = sbase + sl;
    int b = s / 400, p = s - b * 400;
    size_t g = (size_t)b * 4000 + p * 10 + t;
    yus[0][t][sl] = y[g];
    yus[1][t][sl] = u[g];
  }

  bf16x8 wf_h[4][4], wf_l[4][4];
#pragma unroll
  for (int mt = 0; mt < 4; ++mt)
#pragma unroll
    for (int kc = 0; kc < 4; ++kc) {
      size_t g = (size_t)(mh + mt * 16 + r16) * 128 + kc * 32 + quad * 8;
      wf_h[mt][kc] = *(const bf16x8*)(whh_h + g);
      wf_l[mt][kc] = *(const bf16x8*)(whh_l + g);
    }

  float b2r[4][4], war[4][4], wbr[4][4];
#pragma unroll
  for (int mt = 0; mt < 4; ++mt)
#pragma unroll
    for (int r = 0; r < 4; ++r) {
      int ho = mh + mt * 16 + quad * 4 + r;
      war[mt][r] = Wih[ho * 2 + 0];
      wbr[mt][r] = Wih[ho * 2 + 1];
      b2r[mt][r] = bih[ho] + bhh[ho];
    }
  __syncthreads();

  f32x4 acc[4][4];
  for (int t = 0; t < 10; ++t) {
    float yv[4], uv[4];
#pragma unroll
    for (int nt = 0; nt < 4; ++nt) {
      int s = sh + nt * 16 + r16;
      yv[nt] = yus[0][t][s];
      uv[nt] = yus[1][t][s];
    }
#pragma unroll
    for (int mt = 0; mt < 4; ++mt)
#pragma unroll
      for (int nt = 0; nt < 4; ++nt)
#pragma unroll
        for (int r = 0; r < 4; ++r)
          acc[mt][nt][r] = b2r[mt][r] + war[mt][r] * yv[nt] + wbr[mt][r] * uv[nt];

    if (t > 0) {
#pragma unroll
      for (int kc = 0; kc < 4; ++kc) {
        bf16x8 bhf[4], blf[4];
#pragma unroll
        for (int nt = 0; nt < 4; ++nt) {
          int a = (sh + nt * 16 + r16) * 136 + kc * 32 + quad * 8;
          bhf[nt] = *(const bf16x8*)&Hh[a];
          blf[nt] = *(const bf16x8*)&Hl[a];
        }
#pragma unroll
        for (int mt = 0; mt < 4; ++mt)
#pragma unroll
          for (int nt = 0; nt < 4; ++nt) {
            acc[mt][nt] = __builtin_amdgcn_mfma_f32_16x16x32_bf16(wf_h[mt][kc], bhf[nt], acc[mt][nt], 0, 0, 0);
            acc[mt][nt] = __builtin_amdgcn_mfma_f32_16x16x32_bf16(wf_l[mt][kc], bhf[nt], acc[mt][nt], 0, 0, 0);
            acc[mt][nt] = __builtin_amdgcn_mfma_f32_16x16x32_bf16(wf_h[mt][kc], blf[nt], acc[mt][nt], 0, 0, 0);
          }
      }
      __syncthreads();
    }

#pragma unroll
    for (int mt = 0; mt < 4; ++mt)
#pragma unroll
      for (int nt = 0; nt < 4; ++nt) {
        B4 hi4, lo4;
#pragma unroll
        for (int r = 0; r < 4; ++r) {
          float hv = tanh_fast(acc[mt][nt][r]);
          split1(hv, &hi4.u[r], &lo4.u[r]);
        }
        int s = sh + nt * 16 + r16;
        int off = s * 136 + mh + mt * 16 + quad * 4;
        *(ushort4*)&Hh[off] = hi4.s4;
        *(ushort4*)&Hl[off] = lo4.s4;
      }
    __syncthreads();
  }

  for (int idx = tid; idx < 2048; idx += 256) {
    int row = idx >> 4, c = (idx & 15) * 8;
    size_t g = (size_t)(sbase + row) * 128 + c;
    *(bf16x8*)(hnh + g) = *(const bf16x8*)&Hh[row * 136 + c];
    *(bf16x8*)(hnl + g) = *(const bf16x8*)&Hl[row * 136 + c];
  }
}

// ---------------------------------------------------------------------------
// Split-bf16 MFMA GEMM with register-prefetch pipeline (round-5; best
// measured). Block: 128 threads (2 waves), tile 128m x 64n, BK=32.
// ---------------------------------------------------------------------------
template <int EPI>
__global__ __launch_bounds__(128) void mgemm(
    const unsigned short* __restrict__ Agh, const unsigned short* __restrict__ Agl,
    int lda,
    const unsigned short* __restrict__ Wgh, const unsigned short* __restrict__ Wgl,
    const float* __restrict__ bias, const float* __restrict__ res,
    float* __restrict__ C, unsigned short* __restrict__ Ch,
    unsigned short* __restrict__ Cl, int M, int N, int K)
{
  __shared__ unsigned short AhL[128 * 40];
  __shared__ unsigned short AlL[128 * 40];
  __shared__ unsigned short WhL[64 * 40];
  __shared__ unsigned short WlL[64 * 40];
  const int tid = threadIdx.x;
  const int wid = tid >> 6, lane = tid & 63;
  const int quad = lane >> 4, r16 = lane & 15;
  const int m0 = blockIdx.x * 128, n0 = blockIdx.y * 64;
  const int mbase = wid * 64;
  f32x4 acc[4][4] = {};

  int arow[4], acol[4], wrow[2], wcol[2];
  const unsigned short *Aph[4], *Apl[4], *Wph[2], *Wpl[2];
#pragma unroll
  for (int r = 0; r < 4; ++r) {
    int idx = tid + r * 128;
    arow[r] = idx >> 2;
    acol[r] = (idx & 3) * 8;
    Aph[r] = Agh + (size_t)(m0 + arow[r]) * lda + acol[r];
    Apl[r] = Agl + (size_t)(m0 + arow[r]) * lda + acol[r];
  }
#pragma unroll
  for (int r = 0; r < 2; ++r) {
    int idx = tid + r * 128;
    wrow[r] = idx >> 2;
    wcol[r] = (idx & 3) * 8;
    Wph[r] = Wgh + (size_t)(n0 + wrow[r]) * K + wcol[r];
    Wpl[r] = Wgl + (size_t)(n0 + wrow[r]) * K + wcol[r];
  }

  bf16x8 ra_h[4], ra_l[4], rw_h[2], rw_l[2];
#pragma unroll
  for (int r = 0; r < 4; ++r) {
    ra_h[r] = *(const bf16x8*)(Aph[r]);
    ra_l[r] = *(const bf16x8*)(Apl[r]);
  }
#pragma unroll
  for (int r = 0; r < 2; ++r) {
    rw_h[r] = *(const bf16x8*)(Wph[r]);
    rw_l[r] = *(const bf16x8*)(Wpl[r]);
  }

  for (int k0 = 0; k0 < K; k0 += 32) {
#pragma unroll
    for (int r = 0; r < 4; ++r) {
      *(bf16x8*)&AhL[arow[r] * 40 + acol[r]] = ra_h[r];
      *(bf16x8*)&AlL[arow[r] * 40 + acol[r]] = ra_l[r];
    }
#pragma unroll
    for (int r = 0; r < 2; ++r) {
      *(bf16x8*)&WhL[wrow[r] * 40 + wcol[r]] = rw_h[r];
      *(bf16x8*)&WlL[wrow[r] * 40 + wcol[r]] = rw_l[r];
    }
    if (k0 + 32 < K) {
      int kn = k0 + 32;
#pragma unroll
      for (int r = 0; r < 4; ++r) {
        ra_h[r] = *(const bf16x8*)(Aph[r] + kn);
        ra_l[r] = *(const bf16x8*)(Apl[r] + kn);
      }
#pragma unroll
      for (int r = 0; r < 2; ++r) {
        rw_h[r] = *(const bf16x8*)(Wph[r] + kn);
        rw_l[r] = *(const bf16x8*)(Wpl[r] + kn);
      }
    }
    __syncthreads();
    bf16x8 ah[4], al[4], bh[4], bl[4];
#pragma unroll
    for (int t = 0; t < 4; ++t) {
      int ra = (mbase + t * 16 + r16) * 40 + quad * 8;
      ah[t] = *(const bf16x8*)&AhL[ra];
      al[t] = *(const bf16x8*)&AlL[ra];
      int rb = (t * 16 + r16) * 40 + quad * 8;
      bh[t] = *(const bf16x8*)&WhL[rb];
      bl[t] = *(const bf16x8*)&WlL[rb];
    }
#pragma unroll
    for (int mt = 0; mt < 4; ++mt)
#pragma unroll
      for (int nt = 0; nt < 4; ++nt) {
        acc[mt][nt] = __builtin_amdgcn_mfma_f32_16x16x32_bf16(ah[mt], bh[nt], acc[mt][nt], 0, 0, 0);
        acc[mt][nt] = __builtin_amdgcn_mfma_f32_16x16x32_bf16(al[mt], bh[nt], acc[mt][nt], 0, 0, 0);
        acc[mt][nt] = __builtin_amdgcn_mfma_f32_16x16x32_bf16(ah[mt], bl[nt], acc[mt][nt], 0, 0, 0);
      }
    __syncthreads();
  }

#pragma unroll
  for (int mt = 0; mt < 4; ++mt)
#pragma unroll
    for (int nt = 0; nt < 4; ++nt)
#pragma unroll
      for (int r = 0; r < 4; ++r) {
        int m = m0 + mbase + mt * 16 + quad * 4 + r;
        int n = n0 + nt * 16 + r16;
        float v = acc[mt][nt][r];
        if (EPI == 3) {
          v += bias[n];
          int p = m % 400;
          float freq = __expf((float)(n & ~1) * (-9.210340371976184f / 192.f));
          float ang = (float)p * freq;
          v += (n & 1) ? cosf(ang) : sinf(ang);
        }
        if (EPI == 1) v += res[(size_t)m * N + n];
        if (EPI == 2) {
          v = gelu_f(v);
          size_t g = (size_t)m * N + n;
          split1(v, &Ch[g], &Cl[g]);
        } else {
          C[(size_t)m * N + n] = v;
        }
      }
}

// ---------------------------------------------------------------------------
// LayerNorm over 192.
// ---------------------------------------------------------------------------
template <bool BF16OUT>
__global__ __launch_bounds__(256) void ln_kernel(
    const float* __restrict__ x, const float* __restrict__ w,
    float* __restrict__ outf, unsigned short* __restrict__ oh,
    unsigned short* __restrict__ ol)
{
  int token = blockIdx.x * 4 + (threadIdx.x >> 6);
  int lane = threadIdx.x & 63;
  const float* xp = x + (size_t)token * 192;
  float v0 = xp[lane], v1 = xp[lane + 64], v2 = xp[lane + 128];
  float s = v0 + v1 + v2;
  float sq = v0 * v0 + v1 * v1 + v2 * v2;
#pragma unroll
  for (int off = 32; off >= 1; off >>= 1) {
    s += __shfl_xor(s, off, 64);
    sq += __shfl_xor(sq, off, 64);
  }
  float mean = s * (1.f / 192.f);
  float var = sq * (1.f / 192.f) - mean * mean;
  float rstd = rsqrtf(var + 1e-5f);
  float o0 = (v0 - mean) * rstd * w[lane];
  float o1 = (v1 - mean) * rstd * w[lane + 64];
  float o2 = (v2 - mean) * rstd * w[lane + 128];
  size_t base = (size_t)token * 192;
  if (BF16OUT) {
    split1(o0, &oh[base + lane], &ol[base + lane]);
    split1(o1, &oh[base + lane + 64], &ol[base + lane + 64]);
    split1(o2, &oh[base + lane + 128], &ol[base + lane + 128]);
  } else {
    outf[base + lane] = o0;
    outf[base + lane + 64] = o1;
    outf[base + lane + 128] = o2;
  }
}

// ---------------------------------------------------------------------------
// MFMA attention — round-4 body (fences, lstat, single Pst buffer) at
// 512 threads = 8 waves for 2x occupancy. One block per (b,h).
// LDS: KC 32KB + VT 27.1KB + Pst 18.4KB + lstat 0.5KB = ~78KB -> 2 blocks/CU,
// 4 waves/SIMD.
// ---------------------------------------------------------------------------
__global__ __launch_bounds__(512) void attn_kernel(
    const float* __restrict__ qkv, unsigned short* __restrict__ oh,
    unsigned short* __restrict__ ol)
{
  __shared__ unsigned short KC[400 * 40];
  __shared__ unsigned short VTh[16 * 424];
  __shared__ unsigned short VTl[16 * 424];
  __shared__ unsigned short Pst[8][16 * 36 * 2];
  __shared__ float lstat[8][16];
  const int tid = threadIdx.x;
  const int bh = blockIdx.x;
  const int b = bh / 12;
  const int h = bh - b * 12;
  const float* base = qkv + (size_t)b * 400 * 576;

  // zero V pad columns (j = 400..423)
  for (int idx = tid; idx < 16 * 24; idx += 512) {
    int d = idx / 24;
    int j = 400 + idx % 24;
    VTh[d * 424 + j] = 0;
    VTl[d * 424 + j] = 0;
  }
  // stage K (row-major, hi|lo concat) and V (transposed hi/lo)
  for (int it = tid; it < 1600; it += 512) {
    int j = it >> 2, d4 = (it & 3) << 2;
    const float* rp = base + (size_t)j * 576 + h * 16 + d4;
    float4 kv = *(const float4*)(rp + 192);
    float4 vv = *(const float4*)(rp + 384);
    B4 kh, kl;
    split1(kv.x, &kh.u[0], &kl.u[0]);
    split1(kv.y, &kh.u[1], &kl.u[1]);
    split1(kv.z, &kh.u[2], &kl.u[2]);
    split1(kv.w, &kh.u[3], &kl.u[3]);
    *(ushort4*)&KC[j * 40 + d4] = kh.s4;
    *(ushort4*)&KC[j * 40 + 16 + d4] = kl.s4;
    unsigned short vh[4], vl[4];
    split1(vv.x, &vh[0], &vl[0]);
    split1(vv.y, &vh[1], &vl[1]);
    split1(vv.z, &vh[2], &vl[2]);
    split1(vv.w, &vh[3], &vl[3]);
#pragma unroll
    for (int k = 0; k < 4; ++k) {
      VTh[(d4 + k) * 424 + j] = vh[k];
      VTl[(d4 + k) * 424 + j] = vl[k];
    }
  }
  __syncthreads();

  const int wid = tid >> 6, lane = tid & 63;
  const int quad = lane >> 4, r16 = lane & 15;
  unsigned short* Ph = &Pst[wid][0];
  unsigned short* Pl = &Pst[wid][576];

  for (int qt = wid; qt < 25; qt += 8) {
    // ---- Q fragments: [Qh|Ql] and [Ql|Qh] along k
    const float* qp = base + (size_t)(qt * 16 + r16) * 576 + h * 16 + ((quad & 1) * 8);
    float4 q0 = *(const float4*)qp;
    float4 q1 = *(const float4*)(qp + 4);
    float qv[8] = {q0.x, q0.y, q0.z, q0.w, q1.x, q1.y, q1.z, q1.w};
    B8 qh, ql;
#pragma unroll
    for (int i = 0; i < 8; ++i) split1(qv[i], &qh.u[i], &ql.u[i]);
    bf16x8 B1 = (quad < 2) ? qh.v : ql.v;
    bf16x8 B2 = (quad < 2) ? ql.v : qh.v;

    // ---- S^T tiles
    f32x4 acc[25];
#pragma unroll
    for (int jt = 0; jt < 25; ++jt) {
      bf16x8 A = *(const bf16x8*)&KC[(jt * 16 + r16) * 40 + quad * 8];
      f32x4 a = {0.f, 0.f, 0.f, 0.f};
      a = __builtin_amdgcn_mfma_f32_16x16x32_bf16(A, B1, a, 0, 0, 0);
      a = __builtin_amdgcn_mfma_f32_16x16x32_bf16(A, B2, a, 0, 0, 0);
      acc[jt] = a;
    }

    // ---- softmax (scale 1/sqrt(16) = 0.25 folded into exp arg)
    float mx = -INFINITY;
#pragma unroll
    for (int jt = 0; jt < 25; ++jt)
#pragma unroll
      for (int r = 0; r < 4; ++r) mx = fmaxf(mx, acc[jt][r]);
    mx = fmaxf(mx, __shfl_xor(mx, 16, 64));
    mx = fmaxf(mx, __shfl_xor(mx, 32, 64));
    float mm = 0.25f * mx;
    float lsum = 0.f;
#pragma unroll
    for (int jt = 0; jt < 25; ++jt)
#pragma unroll
      for (int r = 0; r < 4; ++r) {
        float p = __expf(fmaf(0.25f, acc[jt][r], -mm));
        acc[jt][r] = p;
        lsum += p;
      }
    lsum += __shfl_xor(lsum, 16, 64);
    lsum += __shfl_xor(lsum, 32, 64);
    float linv = 1.f / lsum;
    if (lane < 16) lstat[wid][r16] = linv;

    // ---- PV over 13 chunks of 32 j (single-buffer bounce, fences pin order)
    f32x4 O = {0.f, 0.f, 0.f, 0.f};
#pragma unroll
    for (int c = 0; c < 13; ++c) {
      {
        B4 ph, pl;
        f32x4 p = acc[2 * c];
        split1(p[0], &ph.u[0], &pl.u[0]);
        split1(p[1], &ph.u[1], &pl.u[1]);
        split1(p[2], &ph.u[2], &pl.u[2]);
        split1(p[3], &ph.u[3], &pl.u[3]);
        *(ushort4*)&Ph[r16 * 36 + quad * 4] = ph.s4;
        *(ushort4*)&Pl[r16 * 36 + quad * 4] = pl.s4;
      }
      if (c < 12) {
        B4 ph, pl;
        f32x4 p = acc[2 * c + 1];
        split1(p[0], &ph.u[0], &pl.u[0]);
        split1(p[1], &ph.u[1], &pl.u[1]);
        split1(p[2], &ph.u[2], &pl.u[2]);
        split1(p[3], &ph.u[3], &pl.u[3]);
        *(ushort4*)&Ph[r16 * 36 + 16 + quad * 4] = ph.s4;
        *(ushort4*)&Pl[r16 * 36 + 16 + quad * 4] = pl.s4;
      } else {
        ushort4 z = {0, 0, 0, 0};
        *(ushort4*)&Ph[r16 * 36 + 16 + quad * 4] = z;
        *(ushort4*)&Pl[r16 * 36 + 16 + quad * 4] = z;
      }
      asm volatile("" ::: "memory");  // keep compiler from reordering LDS r/w
      bf16x8 Ah = *(const bf16x8*)&Ph[r16 * 36 + quad * 8];
      bf16x8 Al = *(const bf16x8*)&Pl[r16 * 36 + quad * 8];
      bf16x8 Vh = *(const bf16x8*)&VTh[r16 * 424 + c * 32 + quad * 8];
      bf16x8 Vl = *(const bf16x8*)&VTl[r16 * 424 + c * 32 + quad * 8];
      O = __builtin_amdgcn_mfma_f32_16x16x32_bf16(Ah, Vh, O, 0, 0, 0);
      O = __builtin_amdgcn_mfma_f32_16x16x32_bf16(Al, Vh, O, 0, 0, 0);
      O = __builtin_amdgcn_mfma_f32_16x16x32_bf16(Ah, Vl, O, 0, 0, 0);
      asm volatile("" ::: "memory");
    }

    // ---- epilogue: O C-layout col=d=r16, row=q_local=quad*4+r
#pragma unroll
    for (int r = 0; r < 4; ++r) {
      float lv = lstat[wid][quad * 4 + r];
      float v = O[r] * lv;
      size_t g = (size_t)(b * 400 + qt * 16 + quad * 4 + r) * 192 + h * 16 + r16;
      split1(v, &oh[g], &ol[g]);
    }
  }
}

// ---------------------------------------------------------------------------
// Mean-pool over seq (400).
// ---------------------------------------------------------------------------
__global__ void pool_kernel(const float* __restrict__ xln, float* __restrict__ pooled)
{
  int b = blockIdx.x;
  int d = threadIdx.x;  // 192
  const float* p = xln + (size_t)b * 400 * 192 + d;
  float s = 0.f;
  for (int t = 0; t < 400; ++t) s += p[(size_t)t * 192];
  pooled[b * 192 + d] = s * (1.f / 400.f);
}

// ---------------------------------------------------------------------------
// Small fp32 GEMM for pooled @ proj_W^T + b (M=64).
// ---------------------------------------------------------------------------
__global__ __launch_bounds__(256) void sgemm_kernel(
    const float* __restrict__ A, const float* __restrict__ W,
    const float* __restrict__ bias, float* __restrict__ C,
    int M, int N, int K)
{
  __shared__ float As[16][128];
  __shared__ float Ws[16][64];
  const int tid = threadIdx.x;
  const int m0 = blockIdx.x * 128;
  const int n0 = blockIdx.y * 64;
  const int tx = tid & 15;
  const int ty = tid >> 4;
  float acc[8][4] = {};

  for (int k0 = 0; k0 < K; k0 += 16) {
    int id = tid;
#pragma unroll
    for (int r = 0; r < 2; ++r, id += 256) {
      int kg = (id & 3) << 2;
      int m = id >> 2;
      float4 v = make_float4(0.f, 0.f, 0.f, 0.f);
      if ((m0 + m) < M)
        v = *(const float4*)(A + (size_t)(m0 + m) * K + k0 + kg);
      As[kg + 0][m] = v.x; As[kg + 1][m] = v.y;
      As[kg + 2][m] = v.z; As[kg + 3][m] = v.w;
    }
    {
      int kg = (tid & 3) << 2;
      int n = tid >> 2;
      float4 v = *(const float4*)(W + (size_t)(n0 + n) * K + k0 + kg);
      Ws[kg + 0][n] = v.x; Ws[kg + 1][n] = v.y;
      Ws[kg + 2][n] = v.z; Ws[kg + 3][n] = v.w;
    }
    __syncthreads();
#pragma unroll
    for (int kk = 0; kk < 16; ++kk) {
      float4 a0 = *(const float4*)&As[kk][ty * 8];
      float4 a1 = *(const float4*)&As[kk][ty * 8 + 4];
      float4 b4 = *(const float4*)&Ws[kk][tx * 4];
      float av[8] = {a0.x, a0.y, a0.z, a0.w, a1.x, a1.y, a1.z, a1.w};
      float bv[4] = {b4.x, b4.y, b4.z, b4.w};
#pragma unroll
      for (int i = 0; i < 8; ++i)
#pragma unroll
        for (int j = 0; j < 4; ++j)
          acc[i][j] += av[i] * bv[j];
    }
    __syncthreads();
  }
  float4 bvz = *(const float4*)(bias + n0 + tx * 4);
#pragma unroll
  for (int i = 0; i < 8; ++i) {
    int m = m0 + ty * 8 + i;
    if (m >= M) continue;
    int n = n0 + tx * 4;
    float4 outv = make_float4(acc[i][0] + bvz.x, acc[i][1] + bvz.y,
                              acc[i][2] + bvz.z, acc[i][3] + bvz.w);
    *(float4*)(C + (size_t)m * N + n) = outv;
  }
}

// ---------------------------------------------------------------------------
// Final LDS scans (chunk-parallel affine recurrence). One block per batch.
// ---------------------------------------------------------------------------
__global__ __launch_bounds__(64) void lds_kernel(
    const float* __restrict__ params, const float* __restrict__ u_new,
    float* __restrict__ out)
{
  __shared__ float P[192];
  __shared__ float ubuf[2048];
  __shared__ float fbuf[2048];
  __shared__ float dv[64][5];
  __shared__ float xin[64][5];
  const int b = blockIdx.x;
  const int c = threadIdx.x;
  for (int k = c; k < 192; k += 64) P[k] = params[b * 192 + k];
  for (int i = c; i < 2048; i += 64) ubuf[i] = u_new[(size_t)b * 2048 + i];
  __syncthreads();

  float A1[25], B1v[5], C1v[5], D1s, w1[29], b1v[29], w2[29], b2s;
  float A2[25], B2v[5], C2v[5], D2s;
#pragma unroll
  for (int i = 0; i < 25; ++i) A1[i] = P[i];
#pragma unroll
  for (int i = 0; i < 5; ++i) B1v[i] = P[25 + i];
#pragma unroll
  for (int i = 0; i < 5; ++i) C1v[i] = P[30 + i];
  D1s = P[35];
#pragma unroll
  for (int i = 0; i < 29; ++i) w1[i] = P[36 + i];
#pragma unroll
  for (int i = 0; i < 29; ++i) b1v[i] = P[65 + i];
#pragma unroll
  for (int i = 0; i < 29; ++i) w2[i] = P[94 + i];
  b2s = P[123];
#pragma unroll
  for (int i = 0; i < 25; ++i) A2[i] = P[124 + i];
#pragma unroll
  for (int i = 0; i < 5; ++i) B2v[i] = P[149 + i];
#pragma unroll
  for (int i = 0; i < 5; ++i) C2v[i] = P[154 + i];
  D2s = P[159];

  const int t0 = c * 32;
  float s1[5] = {0, 0, 0, 0, 0};
  for (int t = 0; t < 32; ++t) {
    float ut = ubuf[t0 + t];
    float ns[5];
#pragma unroll
    for (int i = 0; i < 5; ++i) {
      float a = B1v[i] * ut;
#pragma unroll
      for (int j = 0; j < 5; ++j) a += A1[i * 5 + j] * s1[j];
      ns[i] = a;
    }
#pragma unroll
    for (int i = 0; i < 5; ++i) s1[i] = ns[i];
  }
#pragma unroll
  for (int i = 0; i < 5; ++i) dv[c][i] = s1[i];
  __syncthreads();
  if (c == 0) {
    float Pm[25], T[25];
#pragma unroll
    for (int i = 0; i < 25; ++i) Pm[i] = A1[i];
    for (int it = 0; it < 5; ++it) {
#pragma unroll
      for (int i = 0; i < 5; ++i)
#pragma unroll
        for (int j = 0; j < 5; ++j) {
          float a = 0.f;
#pragma unroll
          for (int k = 0; k < 5; ++k) a += Pm[i * 5 + k] * Pm[k * 5 + j];
          T[i * 5 + j] = a;
        }
#pragma unroll
      for (int i = 0; i < 25; ++i) Pm[i] = T[i];
    }
    float xs[5] = {0, 0, 0, 0, 0};
    for (int cc = 0; cc < 64; ++cc) {
#pragma unroll
      for (int i = 0; i < 5; ++i) xin[cc][i] = xs[i];
      float nx[5];
#pragma unroll
      for (int i = 0; i < 5; ++i) {
        float a = dv[cc][i];
#pragma unroll
        for (int j = 0; j < 5; ++j) a += Pm[i * 5 + j] * xs[j];
        nx[i] = a;
      }
#pragma unroll
      for (int i = 0; i < 5; ++i) xs[i] = nx[i];
    }
  }
  __syncthreads();
#pragma unroll
  for (int i = 0; i < 5; ++i) s1[i] = xin[c][i];
  float s2[5] = {0, 0, 0, 0, 0};
  for (int t = 0; t < 32; ++t) {
    float ut = ubuf[t0 + t];
    float ns[5];
#pragma unroll
    for (int i = 0; i < 5; ++i) {
      float a = B1v[i] * ut;
#pragma unroll
      for (int j = 0; j < 5; ++j) a += A1[i * 5 + j] * s1[j];
      ns[i] = a;
    }
#pragma unroll
    for (int i = 0; i < 5; ++i) s1[i] = ns[i];
    float y1 = D1s * ut;
#pragma unroll
    for (int j = 0; j < 5; ++j) y1 += C1v[j] * s1[j];
    float f = b2s;
#pragma unroll
    for (int k = 0; k < 29; ++k) f += tanh_fast(y1 * w1[k] + b1v[k]) * w2[k];
    fbuf[t0 + t] = f;
#pragma unroll
    for (int i = 0; i < 5; ++i) {
      float a = B2v[i] * f;
#pragma unroll
      for (int j = 0; j < 5; ++j) a += A2[i * 5 + j] * s2[j];
      ns[i] = a;
    }
#pragma unroll
    for (int i = 0; i < 5; ++i) s2[i] = ns[i];
  }
#pragma unroll
  for (int i = 0; i < 5; ++i) dv[c][i] = s2[i];
  __syncthreads();
  if (c == 0) {
    float Pm[25], T[25];
#pragma unroll
    for (int i = 0; i < 25; ++i) Pm[i] = A2[i];
    for (int it = 0; it < 5; ++it) {
#pragma unroll
      for (int i = 0; i < 5; ++i)
#pragma unroll
        for (int j = 0; j < 5; ++j) {
          float a = 0.f;
#pragma unroll
          for (int k = 0; k < 5; ++k) a += Pm[i * 5 + k] * Pm[k * 5 + j];
          T[i * 5 + j] = a;
        }
#pragma unroll
      for (int i = 0; i < 25; ++i) Pm[i] = T[i];
    }
    float xs[5] = {0, 0, 0, 0, 0};
    for (int cc = 0; cc < 64; ++cc) {
#pragma unroll
      for (int i = 0; i < 5; ++i) xin[cc][i] = xs[i];
      float nx[5];
#pragma unroll
      for (int i = 0; i < 5; ++i) {
        float a = dv[cc][i];
#pragma unroll
        for (int j = 0; j < 5; ++j) a += Pm[i * 5 + j] * xs[j];
        nx[i] = a;
      }
#pragma unroll
      for (int i = 0; i < 5; ++i) xs[i] = nx[i];
    }
  }
  __syncthreads();
#pragma unroll
  for (int i = 0; i < 5; ++i) s2[i] = xin[c][i];
  float lsum = 0.f;
  for (int t = 0; t < 32; ++t) {
    float ft = fbuf[t0 + t];
    float ns[5];
#pragma unroll
    for (int i = 0; i < 5; ++i) {
      float a = B2v[i] * ft;
#pragma unroll
      for (int j = 0; j < 5; ++j) a += A2[i * 5 + j] * s2[j];
      ns[i] = a;
    }
#pragma unroll
    for (int i = 0; i < 5; ++i) s2[i] = ns[i];
    float ov = D2s * ft;
#pragma unroll
    for (int j = 0; j < 5; ++j) ov += C2v[j] * s2[j];
    ubuf[t0 + t] = ov;
    lsum += ov;
  }
#pragma unroll
  for (int off = 32; off >= 1; off >>= 1) lsum += __shfl_xor(lsum, off, 64);
  float mean = lsum * (1.f / 2048.f);
  __syncthreads();
  for (int i = c; i < 2048; i += 64)
    out[(size_t)b * 2048 + i] = ubuf[i] - mean;
}

// ---------------------------------------------------------------------------
extern "C" void kernel_launch(void* const* d_in, const int* in_sizes, int n_in,
                              void* d_out, int out_size, void* d_ws, size_t ws_size,
                              hipStream_t stream)
{
  (void)in_sizes; (void)n_in; (void)out_size; (void)ws_size;
  const float* y       = (const float*)d_in[0];
  const float* u       = (const float*)d_in[1];
  const float* u_new   = (const float*)d_in[2];
  const float* rnn_Wih = (const float*)d_in[3];
  const float* rnn_Whh = (const float*)d_in[4];
  const float* rnn_bih = (const float*)d_in[5];
  const float* rnn_bhh = (const float*)d_in[6];
  const float* wte_W   = (const float*)d_in[7];
  const float* wte_b   = (const float*)d_in[8];
  const float* ln1_w   = (const float*)d_in[9];
  const float* Wqkv    = (const float*)d_in[10];
  const float* Wo      = (const float*)d_in[11];
  const float* ln2_w   = (const float*)d_in[12];
  const float* Wfc     = (const float*)d_in[13];
  const float* Wproj   = (const float*)d_in[14];
  const float* lnf_w   = (const float*)d_in[15];
  const float* proj_W  = (const float*)d_in[16];
  const float* proj_b  = (const float*)d_in[17];
  float* out = (float*)d_out;
  char* wsb = (char*)d_ws;

  // ---- workspace layout ----
  float* x      = (float*)wsb;                               // 4,915,200 f
  float* bigf   = x + 4915200;                               // 14,745,600 f
  float* pooled = bigf + 14745600;                           // 12,288 f
  float* paramsv = pooled + 12288;                           // 12,288 f
  unsigned short* aA_h = (unsigned short*)(paramsv + 12288); // 25600*192
  unsigned short* aA_l = aA_h + 4915200;
  unsigned short* aB_h = aA_l + 4915200;                     // 25600*768
  unsigned short* aB_l = aB_h + 19660800;
  unsigned short* w_h  = aB_l + 19660800;                    // 3,563,520
  unsigned short* w_l  = w_h + 3563520;
  unsigned short* whh_h = w_l + 3563520;                     // 16,384
  unsigned short* whh_l = whh_h + 16384;
  const size_t OFF_ENC = 0;
  const size_t OFF_QKV = 24576;
  const size_t OFF_WO  = 909312;
  const size_t OFF_FC  = 1204224;
  const size_t OFF_PRJ = 2383872;

  cvt_kernel<<<(6144 + 255) / 256, 256, 0, stream>>>(wte_W, w_h + OFF_ENC, w_l + OFF_ENC, 6144);
  cvt_kernel<<<(221184 + 255) / 256, 256, 0, stream>>>(Wqkv, w_h + OFF_QKV, w_l + OFF_QKV, 221184);
  cvt_kernel<<<(73728 + 255) / 256, 256, 0, stream>>>(Wo, w_h + OFF_WO, w_l + OFF_WO, 73728);
  cvt_kernel<<<(294912 + 255) / 256, 256, 0, stream>>>(Wfc, w_h + OFF_FC, w_l + OFF_FC, 294912);
  cvt_kernel<<<(294912 + 255) / 256, 256, 0, stream>>>(Wproj, w_h + OFF_PRJ, w_l + OFF_PRJ, 294912);
  cvt_kernel<<<16, 256, 0, stream>>>(rnn_Whh, whh_h, whh_l, 4096);

  rnn_kernel<<<200, 256, 0, stream>>>(y, u, whh_h, whh_l, rnn_Wih, rnn_bih, rnn_bhh, aA_h, aA_l);

  mgemm<3><<<dim3(200, 3), 128, 0, stream>>>(
      aA_h, aA_l, 128, w_h + OFF_ENC, w_l + OFF_ENC, wte_b, nullptr,
      x, nullptr, nullptr, 25600, 192, 128);

  for (int l = 0; l < 8; ++l) {
    ln_kernel<true><<<6400, 256, 0, stream>>>(x, ln1_w + l * 192, nullptr, aA_h, aA_l);
    mgemm<0><<<dim3(200, 9), 128, 0, stream>>>(
        aA_h, aA_l, 192, w_h + OFF_QKV + (size_t)l * 110592, w_l + OFF_QKV + (size_t)l * 110592,
        nullptr, nullptr, bigf, nullptr, nullptr, 25600, 576, 192);
    attn_kernel<<<768, 512, 0, stream>>>(bigf, aA_h, aA_l);
    mgemm<1><<<dim3(200, 3), 128, 0, stream>>>(
        aA_h, aA_l, 192, w_h + OFF_WO + (size_t)l * 36864, w_l + OFF_WO + (size_t)l * 36864,
        nullptr, x, x, nullptr, nullptr, 25600, 192, 192);
    ln_kernel<true><<<6400, 256, 0, stream>>>(x, ln2_w + l * 192, nullptr, aA_h, aA_l);
    mgemm<2><<<dim3(200, 12), 128, 0, stream>>>(
        aA_h, aA_l, 192, w_h + OFF_FC + (size_t)l * 147456, w_l + OFF_FC + (size_t)l * 147456,
        nullptr, nullptr, nullptr, aB_h, aB_l, 25600, 768, 192);
    mgemm<1><<<dim3(200, 3), 128, 0, stream>>>(
        aB_h, aB_l, 768, w_h + OFF_PRJ + (size_t)l * 147456, w_l + OFF_PRJ + (size_t)l * 147456,
        nullptr, x, x, nullptr, nullptr, 25600, 192, 768);
  }

  ln_kernel<false><<<6400, 256, 0, stream>>>(x, lnf_w, bigf, nullptr, nullptr);
  pool_kernel<<<64, 192, 0, stream>>>(bigf, pooled);
  sgemm_kernel<<<dim3(1, 3), 256, 0, stream>>>(pooled, proj_W, proj_b, paramsv, 64, 192, 192);
  lds_kernel<<<64, 64, 0, stream>>>(paramsv, u_new, out);
}